// Round 3
// baseline (46.944 us; speedup 1.0000x reference)
//
#include <hip/hip_runtime.h>
#include <math.h>

#pragma clang fp contract(off)

#define IMRES 128
#define MESH 20
#define NVERT (MESH*MESH)
#define NCELL ((MESH-1)*(MESH-1))
#define NTRI (2*NCELL)
#define RGBRES 128
#define BCGRES 384
#define BATCH 2
#define TRI_F 12
#define CHUNKS 8
#define CH_TRI 91    // ceil(722/8)
#define PPB 32       // pixels per block
#define BIGF 1000000000.0f

__device__ __forceinline__ void mm3(const float* A, const float* B, float* C){
#pragma unroll
  for (int i=0;i<3;++i)
#pragma unroll
    for (int j=0;j<3;++j)
      C[i*3+j] = A[i*3+0]*B[0*3+j] + A[i*3+1]*B[1*3+j] + A[i*3+2]*B[2*3+j];
}

// One block, 1024 threads: sparse gaussian blur (only the 40 rows x 40 cols the
// mesh samples), bilinear-sample 400 verts, rotate+project per batch, emit
// per-(batch,tri) raster records:
// [v1x,v1y,d21x,d21y, v2x,v2y,d02x,d02y, dA,dB,dC, inv_as]
__global__ __launch_bounds__(1024)
void prep_kernel(const float* __restrict__ img,
                 const float* __restrict__ angles,
                 float* __restrict__ tri){
  __shared__ float skw[13];
  __shared__ int   rcIdx[40];                 // row/col texel indices (square -> same)
  __shared__ float tmp[40][IMRES][3];         // H-pass at needed rows, 61440 B
  __shared__ float out2[40][40][3];           // full blur at needed texels, 19200 B
  __shared__ float vnd[BATCH*NVERT*3];        // ndcx, ndcy, z, 9600 B
  const int tid = threadIdx.x;
  if (tid == 0){
    float s = 0.0f;
    float w[13];
#pragma unroll
    for (int t=0;t<13;++t){
      float x = (float)(t-6)/2.0f;
      w[t] = expf(-0.5f*(x*x)); s += w[t];
    }
#pragma unroll
    for (int t=0;t<13;++t) skw[t] = w[t]/s;
  }
  if (tid < 40){
    int vi = tid >> 1;
    float u = (float)((double)vi/19.0);       // vertuv computed in f64, cast f32
    float x = u*127.0f;
    int x0 = (int)fminf(fmaxf(floorf(x),0.0f),126.0f);
    rcIdx[tid] = x0 + (tid & 1);
  }
  __syncthreads();
  // Phase A: H-pass. tmp[r][x][ch] = sum_t k[t]*img[clamp(R[r]-6+t)][x][ch]
  for (int it = tid; it < 40*IMRES*3; it += 1024){
    int ch = it % 3;
    int x  = (it/3) % IMRES;
    int r  = it / (IMRES*3);
    int y0 = rcIdx[r];
    float acc = 0.0f;
#pragma unroll
    for (int t=0;t<13;++t){
      int p = min(max(y0-6+t,0), IMRES-1);
      acc = acc + skw[t]*img[(p*IMRES + x)*3 + ch];
    }
    tmp[r][x][ch] = acc;
  }
  __syncthreads();
  // Phase B: W-pass at needed cols. out2[r][cc][ch]
  for (int it = tid; it < 40*40*3; it += 1024){
    int ch = it % 3;
    int cc = (it/3) % 40;
    int r  = it / 120;
    int x0 = rcIdx[cc];
    float acc = 0.0f;
#pragma unroll
    for (int t=0;t<13;++t){
      int p = min(max(x0-6+t,0), IMRES-1);
      acc = acc + skw[t]*tmp[r][p][ch];
    }
    out2[r][cc][ch] = acc;
  }
  __syncthreads();
  // Phase C: bilinear-sample verts, rotate, project.
  const float PI_F = 3.14159274101257324f;   // float32(np.pi)
  const float F    = 11.4300523027613427f;   // 1/tan(5 deg)
  const float DIST = 5.7150261513806713f;    // 0.5/tan(5 deg)
  for (int job = tid; job < BATCH*NVERT; job += 1024){
    int b = job / NVERT, v = job % NVERT;
    int vi = v / MESH, vj = v % MESH;
    float u  = (float)((double)vj/19.0);
    float vv = (float)((double)vi/19.0);
    float x = u*127.0f, y = vv*127.0f;
    int x0i = rcIdx[2*vj], y0i = rcIdx[2*vi];
    float fx = x-(float)x0i, fy = y-(float)y0i;
    float p[3];
#pragma unroll
    for (int ch=0; ch<3; ++ch){
      float t00 = out2[2*vi  ][2*vj  ][ch];
      float t01 = out2[2*vi  ][2*vj+1][ch];
      float t10 = out2[2*vi+1][2*vj  ][ch];
      float t11 = out2[2*vi+1][2*vj+1][ch];
      p[ch] = (t00*(1.0f-fx)+t01*fx)*(1.0f-fy) + (t10*(1.0f-fx)+t11*fx)*fy;
    }
    float lo0 = (-60.0f*PI_F)/180.0f, hi0 = (60.0f*PI_F)/180.0f;
    float lo1 = (-90.0f*PI_F)/180.0f, hi1 = (90.0f*PI_F)/180.0f;
    float ax = angles[b*3+0]*(hi0-lo0)+lo0;
    float ay = angles[b*3+1]*(hi1-lo1)+lo1;
    float az = 0.0f; // angle-z range is [0,0]
    float cx=cosf(ax), sx=sinf(ax);
    float cy=cosf(ay), sy=sinf(ay);
    float cz=cosf(az), sz=sinf(az);
    float Rx[9]={1.f,0.f,0.f,  0.f,cx,-sx,  0.f,sx,cx};
    float Ry[9]={cy,0.f,sy,    0.f,1.f,0.f, -sy,0.f,cy};
    float Rz[9]={cz,-sz,0.f,   sz,cz,0.f,   0.f,0.f,1.f};
    float M1[9], R[9];
    mm3(Rz,Ry,M1); mm3(M1,Rx,R);
    float X0 = R[0]*p[0]+R[1]*p[1]+R[2]*p[2];
    float X1 = R[3]*p[0]+R[4]*p[1]+R[5]*p[2];
    float X2 = R[6]*p[0]+R[7]*p[1]+R[8]*p[2] + DIST;
    vnd[(b*NVERT+v)*3+0] = (F*X0)/X2;
    vnd[(b*NVERT+v)*3+1] = (F*X1)/X2;
    vnd[(b*NVERT+v)*3+2] = X2;
  }
  __syncthreads();
  // Phase D: triangle records.
  for (int job=tid; job<BATCH*NTRI; job+=1024){
    int b = job / NTRI, t = job % NTRI;
    int i0,i1,i2;
    if (t < NCELL){ int r=t/19, cc=t%19; i0=r*MESH+cc; i1=(r+1)*MESH+cc; i2=r*MESH+cc+1; }
    else { int tt=t-NCELL; int r=tt/19, cc=tt%19; i0=(r+1)*MESH+cc; i1=(r+1)*MESH+cc+1; i2=r*MESH+cc+1; }
    const float* V0=&vnd[(b*NVERT+i0)*3];
    const float* V1=&vnd[(b*NVERT+i1)*3];
    const float* V2=&vnd[(b*NVERT+i2)*3];
    float v0x=V0[0], v0y=V0[1], z0=V0[2];
    float v1x=V1[0], v1y=V1[1], z1=V1[2];
    float v2x=V2[0], v2y=V2[1], z2=V2[2];
    float area = (v1x-v0x)*(v2y-v0y) - (v1y-v0y)*(v2x-v0x);
    bool valid = (fabsf(area) > 1e-6f);
    float as = valid ? area : 1.0f;
    float inv = 1.0f/as;
    float d21x = v2x-v1x, d21y = v2y-v1y;
    float d02x = v0x-v2x, d02y = v0y-v2y;
    float dz0 = z0-z2, dz1 = z1-z2;
    float dA = (-d21y*dz0 - d02y*dz1)*inv;
    float dB = ( d21x*dz0 + d02x*dz1)*inv;
    float C0 = d21y*v1x - d21x*v1y;
    float C1 = d02y*v2x - d02x*v2y;
    float dC = z2 + (C0*dz0 + C1*dz1)*inv;
    if (!valid){ dA=0.0f; dB=0.0f; dC=BIGF; inv=__uint_as_float(0x7fc00000u); }
    float* T = &tri[(b*NTRI+t)*TRI_F];
    T[0]=v1x; T[1]=v1y; T[2]=d21x; T[3]=d21y;
    T[4]=v2x; T[5]=v2y; T[6]=d02x; T[7]=d02y;
    T[8]=dA;  T[9]=dB;  T[10]=dC;  T[11]=inv;
  }
}

// 32 pixels per block, 8 waves; each wave covers a 91-triangle chunk; LDS argmin reduce.
__global__ __launch_bounds__(256)
void raster_kernel(const float* __restrict__ tri,
                   const float* __restrict__ angles,
                   const float* __restrict__ rgb,
                   const float* __restrict__ bcg,
                   float* __restrict__ out){
  __shared__ float4 lt4[NTRI*3];     // 34656 B
  __shared__ float sdep[256];
  __shared__ int   sidx[256];
  float* lt = (float*)lt4;
  const int b = blockIdx.y;
  const float* tb = tri + b*NTRI*TRI_F;
  {
    const float4* src = (const float4*)tb;
    for (int k=threadIdx.x; k<NTRI*3; k+=256) lt4[k]=src[k];
  }
  __syncthreads();
  const int lane  = threadIdx.x & (PPB-1);
  const int chunk = threadIdx.x / PPB;
  const int pix = blockIdx.x*PPB + lane;
  const int i = pix>>7, j = pix&127;
  const float px = (((float)j+0.5f)/128.0f)*2.0f - 1.0f; // exact (pow2)
  const float py = (((float)i+0.5f)/128.0f)*2.0f - 1.0f;

  float bestd = BIGF; int bestt = 0;
  const int t0 = chunk*CH_TRI;
  const int t1 = (t0+CH_TRI < NTRI) ? t0+CH_TRI : NTRI;
  for (int t=t0; t<t1; ++t){
    float4 q0 = lt4[t*3+0];
    float4 q1 = lt4[t*3+1];
    float4 q2 = lt4[t*3+2];
    float e0 = q0.z*(py-q0.y) - q0.w*(px-q0.x);
    float e1 = q1.z*(py-q1.y) - q1.w*(px-q1.x);
    float w0 = e0*q2.w, w1 = e1*q2.w;
    float w2 = 1.0f - w0 - w1;
    bool inside = (w0>=0.0f) && (w1>=0.0f) && (w2>=0.0f); // NaN -> false
    float d = q2.x*px + q2.y*py + q2.z;
    d = inside ? d : BIGF;
    if (d < bestd){ bestd=d; bestt=t; }  // strict < == first occurrence in chunk
  }
  sdep[threadIdx.x] = bestd; sidx[threadIdx.x] = bestt;
  __syncthreads();
  if (threadIdx.x >= PPB) return;
#pragma unroll
  for (int c=1;c<CHUNKS;++c){
    float d = sdep[c*PPB+lane]; int t = sidx[c*PPB+lane];
    if (d < bestd || (d == bestd && t < bestt)) { bestd=d; bestt=t; }
  }
  bool mask = bestd < BIGF;

  // recompute barycentrics of the winning triangle (same exprs as main loop)
  const float* T = &lt[bestt*TRI_F];
  float e0 = T[2]*(py-T[1]) - T[3]*(px-T[0]);
  float e1 = T[6]*(py-T[5]) - T[7]*(px-T[4]);
  float w0 = e0*T[11], w1 = e1*T[11];
  float w2 = 1.0f - w0 - w1;

  int t=bestt, i0,i1,i2;
  if (t<NCELL){ int r=t/19, cc=t%19; i0=r*MESH+cc; i1=(r+1)*MESH+cc; i2=r*MESH+cc+1; }
  else { int tt=t-NCELL; int r=tt/19, cc=tt%19; i0=(r+1)*MESH+cc; i1=(r+1)*MESH+cc+1; i2=r*MESH+cc+1; }
  float u0=(float)((double)(i0%MESH)/19.0), q0=(float)((double)(i0/MESH)/19.0);
  float u1=(float)((double)(i1%MESH)/19.0), q1=(float)((double)(i1/MESH)/19.0);
  float u2=(float)((double)(i2%MESH)/19.0), q2=(float)((double)(i2/MESH)/19.0);
  float uu_ = (w0*u0+w1*u1)+w2*u2;
  float vv_ = (w0*q0+w1*q1)+w2*q2;
  uu_ = fminf(fmaxf(uu_,0.0f),1.0f);   // fmaxf/fminf sanitize NaN -> finite
  vv_ = fminf(fmaxf(vv_,0.0f),1.0f);

  float col[3];
  {
    float x = uu_*127.0f, y = vv_*127.0f;
    int x0=(int)fminf(fmaxf(floorf(x),0.0f),126.0f);
    int y0=(int)fminf(fmaxf(floorf(y),0.0f),126.0f);
    float fx=x-(float)x0, fy=y-(float)y0;
#pragma unroll
    for(int ch=0;ch<3;++ch){
      float t00=rgb[(y0*RGBRES+x0)*3+ch];
      float t01=rgb[(y0*RGBRES+x0+1)*3+ch];
      float t10=rgb[((y0+1)*RGBRES+x0)*3+ch];
      float t11=rgb[((y0+1)*RGBRES+x0+1)*3+ch];
      col[ch]=(t00*(1.0f-fx)+t01*fx)*(1.0f-fy)+(t10*(1.0f-fx)+t11*fx)*fy;
    }
  }
  float minb = fminf(fminf(w0,w1),w2);
  float alpha = mask ? (1.0f/(1.0f+expf(-(minb/0.05f)))) : 0.0f;

  const float RH   = (float)(128.0/384.0);
  const float OMRH = (float)(1.0-128.0/384.0);
  float y1 = OMRH*angles[b*3+0];
  float x1 = OMRH*angles[b*3+1];
  float tu = (float)j/127.0f, tv = (float)i/127.0f;
  float bu = fminf(fmaxf(x1 + RH*tu,0.0f),1.0f);
  float bv = fminf(fmaxf(y1 + RH*tv,0.0f),1.0f);
  float bg[3];
  {
    float x=bu*383.0f, y=bv*383.0f;
    int x0=(int)fminf(fmaxf(floorf(x),0.0f),382.0f);
    int y0=(int)fminf(fmaxf(floorf(y),0.0f),382.0f);
    float fx=x-(float)x0, fy=y-(float)y0;
#pragma unroll
    for(int ch=0;ch<3;++ch){
      float t00=bcg[(y0*BCGRES+x0)*3+ch];
      float t01=bcg[(y0*BCGRES+x0+1)*3+ch];
      float t10=bcg[((y0+1)*BCGRES+x0)*3+ch];
      float t11=bcg[((y0+1)*BCGRES+x0+1)*3+ch];
      bg[ch]=(t00*(1.0f-fx)+t01*fx)*(1.0f-fy)+(t10*(1.0f-fx)+t11*fx)*fy;
    }
  }
  float* o = &out[((b*IMRES+i)*IMRES+j)*3];
#pragma unroll
  for(int ch=0;ch<3;++ch) o[ch] = alpha*col[ch] + (1.0f-alpha)*bg[ch];
}

extern "C" void kernel_launch(void* const* d_in, const int* in_sizes, int n_in,
                              void* d_out, int out_size, void* d_ws, size_t ws_size,
                              hipStream_t stream) {
  const float* angles = (const float*)d_in[0];
  const float* xyz    = (const float*)d_in[1];
  const float* rgb    = (const float*)d_in[2];
  const float* bcg    = (const float*)d_in[3];
  float* out = (float*)d_out;
  float* tri = (float*)d_ws;         // 2*722*12 = 17328 f32
  prep_kernel<<<1, 1024, 0, stream>>>(xyz, angles, tri);
  dim3 g(IMRES*IMRES/PPB, BATCH);
  raster_kernel<<<g, 256, 0, stream>>>(tri, angles, rgb, bcg, out);
}